// Round 14
// baseline (185.162 us; speedup 1.0000x reference)
//
#include <hip/hip_runtime.h>

#define HH 64
#define WW 64
#define S  68          // padded LDS row stride (floats)
#define PH 66          // padded rows (1-px zero frame)
#define NLQ 10
#define NP  5          // channel pairs
#define NR 8           // rows per thread (512 threads = 8 waves = 2/SIMD)

typedef float f32x2 __attribute__((ext_vector_type(2)));

// One block per image (grid=256 = 1 block/CU). Thread t: column x=t&63, wave
// yg owns image rows y0..y0+7. v lives in registers (vv[10] = col x of rows
// y0-1..y0+8); horizontal neighbors via wave shuffles; vertical halo via a
// tiny parity LDS buffer (2 rows/wave).
//
// R20 failed correctness (q absmax 0.148, critic passed = LOCALIZED errors).
// Halo protocol + tap mapping re-derived correct; the suspect is __shfl_up/
// down lowering on wave64 (lane-group boundary behavior). R21 hardens:
//  - horizontal exchange via EXPLICIT ds_bpermute (index ((x-+1)&63)<<2,
//    then select 0 at the x=0/63 frame) - unambiguous wave64 semantics.
//  - vertical halo: second barrier after halo reads (protocol safe even
//    without the parity argument; parity kept).
// Numerics otherwise identical to the passing R18 (same fma order/taps).
//
// Step-time model (R12-R19): pk_fma is 4cyc (full FLOP rate, half issue
// density); the ~5760cyc/step floor of the LDS-tiled versions was
// FMA(2880) + serialized LDS burst(~1500) + barrier drain(~1400). This
// structure removes ~240 ds_reads/step -> predicted ~1.6-2.0us/step.
__global__ __launch_bounds__(512)
__attribute__((amdgpu_waves_per_eu(2, 2)))
void vin_fused(
    const float* __restrict__ X,    // [B,2,64,64]
    const float* __restrict__ Wh,   // [150,2,3,3]
    const float* __restrict__ bh,   // [150]
    const float* __restrict__ Wr,   // [150]
    const float* __restrict__ Wq,   // [10,1,3,3]
    const float* __restrict__ wtr,  // [10,1,3,3] transition
    const float* __restrict__ Wc,   // [4096]
    const float* __restrict__ bc,   // [1]
    float* __restrict__ out)        // [256 critic] ++ [256*40960 q]
{
  __shared__ float vb[2][PH * S];     // X staging (r conv inputs)
  __shared__ float rb[PH * S];        // r (q0 conv input)
  __shared__ float hv[2][16][64];     // K-loop halo rows (parity, 2/wave)
  __shared__ float Wef[19];
  __shared__ float Wpart[152];
  __shared__ float red[8];

  const int b  = blockIdx.x;
  const int t  = threadIdx.x;
  const int x  = t & 63;
  const int yg = t >> 6;
  const int y0 = yg * NR;
  const int base0 = y0 * S + x;   // padded (y0, x) = window top-left

  // lane indices for explicit bpermute (byte addr = lane*4)
  const int idxL = ((x - 1) & 63) << 2;   // x==0 wraps to 63; selected away
  const int idxR = ((x + 1) & 63) << 2;   // x==63 wraps to 0; selected away

  // ---- zero LDS (frames must be 0; interiors overwritten) ----
  {
    float* vbf = &vb[0][0];
    for (int i = t; i < 2 * PH * S; i += 512) vbf[i] = 0.f;
    for (int i = t; i < PH * S; i += 512) rb[i] = 0.f;
  }
  __syncthreads();

  // ---- stage X into vb interiors; collapse 150-ch conv to Wef[19] ----
  const float* Xb = X + (size_t)b * (2 * HH * WW);
  for (int i = t; i < HH * WW; i += 512) {
    const int yy = i >> 6, xx = i & 63;
    vb[0][(yy + 1) * S + xx + 1] = Xb[i];
    vb[1][(yy + 1) * S + xx + 1] = Xb[HH * WW + i];
  }
  if (t < 152) {                       // parallel collapse: 19 outputs x 8 parts
    const int i = t >> 3, part = t & 7;
    float s = 0.f;
    if (i < 18) {
      for (int c = part; c < 150; c += 8) s += Wr[c] * Wh[c * 18 + i];
    } else {
      for (int c = part; c < 150; c += 8) s += Wr[c] * bh[c];
    }
    Wpart[t] = s;
  }
  __syncthreads();
  if (t < 19) {
    float s = 0.f;
#pragma unroll
    for (int k = 0; k < 8; ++k) s += Wpart[t * 8 + k];
    Wef[t] = s;
  }
  __syncthreads();

  // ---- r = conv(X, Weff, pad=1) + beff -> rb ----
  {
    float We[19];
#pragma unroll
    for (int i = 0; i < 19; ++i) We[i] = Wef[i];
#pragma unroll
    for (int j = 0; j < NR; ++j) {
      const int tb = base0 + j * S;
      float s = We[18];
#pragma unroll
      for (int dy = 0; dy < 3; ++dy)
#pragma unroll
        for (int dx = 0; dx < 3; ++dx) {
          const int idx = tb + dy * S + dx;
          s = fmaf(vb[0][idx], We[dy * 3 + dx], s);
          s = fmaf(vb[1][idx], We[9 + dy * 3 + dx], s);
        }
      rb[tb + S + 1] = s;
    }
  }
  __syncthreads();

  // ---- q0 = conv(r, Wq, pad=1) -> q0p pairs; v_init -> vv regs ----
  f32x2 q0p[NR][NP];
  float vv[10];                 // vv[0]=row y0-1 halo, vv[1..8]=own, vv[9]=halo
  {
    float win[NR + 2][3];
#pragma unroll
    for (int rr = 0; rr < NR + 2; ++rr) {
      const int a = base0 + rr * S;
      win[rr][0] = rb[a];
      win[rr][1] = rb[a + 1];
      win[rr][2] = rb[a + 2];
    }
    f32x2 mm[NR];
#pragma unroll
    for (int p = 0; p < NP; ++p) {
      f32x2 w[9];
#pragma unroll
      for (int k = 0; k < 9; ++k)
        w[k] = (f32x2){ Wq[(2 * p) * 9 + k], Wq[(2 * p + 1) * 9 + k] };
#pragma unroll
      for (int j = 0; j < NR; ++j) {
        f32x2 acc = (f32x2){0.f, 0.f};
#pragma unroll
        for (int dy = 0; dy < 3; ++dy)
#pragma unroll
          for (int dx = 0; dx < 3; ++dx) {
            const float wv = win[j + dy][dx];
            acc = __builtin_elementwise_fma(w[dy * 3 + dx], (f32x2){wv, wv}, acc);
          }
        q0p[j][p] = acc;
        mm[j] = (p == 0) ? acc : __builtin_elementwise_max(mm[j], acc);
      }
    }
#pragma unroll
    for (int j = 0; j < NR; ++j) vv[j + 1] = fmaxf(mm[j].x, mm[j].y);
  }

  // ---- transition weight pairs (persistent) ----
  f32x2 wtp[NP][9];
#pragma unroll
  for (int p = 0; p < NP; ++p)
#pragma unroll
    for (int k = 0; k < 9; ++k)
      wtp[p][k] = (f32x2){ wtr[(2 * p) * 9 + k], wtr[(2 * p + 1) * 9 + k] };

  __syncthreads();   // staging done; hv safe to use

  // ---- K-loop: 39 v-updates, all state in registers ----
#pragma unroll 1
  for (int it = 0; it < 39; ++it) {
    const int pb = it & 1;
    // vertical halo exchange: write own top/bottom, barrier, read, barrier
    hv[pb][yg * 2][x]     = vv[1];
    hv[pb][yg * 2 + 1][x] = vv[8];
    __syncthreads();
    vv[0] = (yg > 0) ? hv[pb][yg * 2 - 1][x] : 0.f;
    vv[9] = (yg < 7) ? hv[pb][yg * 2 + 2][x] : 0.f;
    __syncthreads();   // reads complete before anyone's next-iteration writes

    // horizontal neighbors via explicit wave64 bpermute (frame = 0)
    float vL[10], vR[10];
#pragma unroll
    for (int r = 0; r < 10; ++r) {
      const float bl = __int_as_float(
          __builtin_amdgcn_ds_bpermute(idxL, __float_as_int(vv[r])));
      const float br = __int_as_float(
          __builtin_amdgcn_ds_bpermute(idxR, __float_as_int(vv[r])));
      vL[r] = (x == 0)  ? 0.f : bl;
      vR[r] = (x == 63) ? 0.f : br;
    }

    f32x2 mm[NR];
#pragma unroll
    for (int p = 0; p < NP; ++p) {
      f32x2 w[9];
#pragma unroll
      for (int k = 0; k < 9; ++k) w[k] = wtp[p][k];
#pragma unroll
      for (int j = 0; j < NR; ++j) {
        f32x2 acc = q0p[j][p];
        acc = __builtin_elementwise_fma(w[0], (f32x2){vL[j],     vL[j]},     acc);
        acc = __builtin_elementwise_fma(w[1], (f32x2){vv[j],     vv[j]},     acc);
        acc = __builtin_elementwise_fma(w[2], (f32x2){vR[j],     vR[j]},     acc);
        acc = __builtin_elementwise_fma(w[3], (f32x2){vL[j + 1], vL[j + 1]}, acc);
        acc = __builtin_elementwise_fma(w[4], (f32x2){vv[j + 1], vv[j + 1]}, acc);
        acc = __builtin_elementwise_fma(w[5], (f32x2){vR[j + 1], vR[j + 1]}, acc);
        acc = __builtin_elementwise_fma(w[6], (f32x2){vL[j + 2], vL[j + 2]}, acc);
        acc = __builtin_elementwise_fma(w[7], (f32x2){vv[j + 2], vv[j + 2]}, acc);
        acc = __builtin_elementwise_fma(w[8], (f32x2){vR[j + 2], vR[j + 2]}, acc);
        mm[j] = (p == 0) ? acc : __builtin_elementwise_max(mm[j], acc);
      }
    }
#pragma unroll
    for (int j = 0; j < NR; ++j) vv[j + 1] = fmaxf(mm[j].x, mm[j].y);
  }

  // ---- final iteration (it=39): emit q + critic dot ----
  {
    const int pb = 39 & 1;
    hv[pb][yg * 2][x]     = vv[1];
    hv[pb][yg * 2 + 1][x] = vv[8];
    __syncthreads();
    vv[0] = (yg > 0) ? hv[pb][yg * 2 - 1][x] : 0.f;
    vv[9] = (yg < 7) ? hv[pb][yg * 2 + 2][x] : 0.f;
    __syncthreads();

    float vL[10], vR[10];
#pragma unroll
    for (int r = 0; r < 10; ++r) {
      const float bl = __int_as_float(
          __builtin_amdgcn_ds_bpermute(idxL, __float_as_int(vv[r])));
      const float br = __int_as_float(
          __builtin_amdgcn_ds_bpermute(idxR, __float_as_int(vv[r])));
      vL[r] = (x == 0)  ? 0.f : bl;
      vR[r] = (x == 63) ? 0.f : br;
    }

    float wcv[NR];
#pragma unroll
    for (int j = 0; j < NR; ++j) wcv[j] = Wc[(y0 + j) * WW + x];

    float* qo = out + 256 + (size_t)b * (NLQ * HH * WW) + y0 * WW + x;
    f32x2 mm[NR];
#pragma unroll
    for (int p = 0; p < NP; ++p) {
      f32x2 w[9];
#pragma unroll
      for (int k = 0; k < 9; ++k) w[k] = wtp[p][k];
#pragma unroll
      for (int j = 0; j < NR; ++j) {
        f32x2 acc = q0p[j][p];
        acc = __builtin_elementwise_fma(w[0], (f32x2){vL[j],     vL[j]},     acc);
        acc = __builtin_elementwise_fma(w[1], (f32x2){vv[j],     vv[j]},     acc);
        acc = __builtin_elementwise_fma(w[2], (f32x2){vR[j],     vR[j]},     acc);
        acc = __builtin_elementwise_fma(w[3], (f32x2){vL[j + 1], vL[j + 1]}, acc);
        acc = __builtin_elementwise_fma(w[4], (f32x2){vv[j + 1], vv[j + 1]}, acc);
        acc = __builtin_elementwise_fma(w[5], (f32x2){vR[j + 1], vR[j + 1]}, acc);
        acc = __builtin_elementwise_fma(w[6], (f32x2){vL[j + 2], vL[j + 2]}, acc);
        acc = __builtin_elementwise_fma(w[7], (f32x2){vv[j + 2], vv[j + 2]}, acc);
        acc = __builtin_elementwise_fma(w[8], (f32x2){vR[j + 2], vR[j + 2]}, acc);
        qo[(2 * p)     * (HH * WW) + j * WW] = acc.x;
        qo[(2 * p + 1) * (HH * WW) + j * WW] = acc.y;
        mm[j] = (p == 0) ? acc : __builtin_elementwise_max(mm[j], acc);
      }
    }
    float acc_c = 0.f;
#pragma unroll
    for (int j = 0; j < NR; ++j)
      acc_c = fmaf(fmaxf(mm[j].x, mm[j].y), wcv[j], acc_c);

    // ---- block-reduce critic ----
#pragma unroll
    for (int off = 32; off > 0; off >>= 1) acc_c += __shfl_down(acc_c, off);
    if (x == 0) red[yg] = acc_c;
    __syncthreads();
    if (t == 0) {
      float s = bc[0];
#pragma unroll
      for (int i = 0; i < 8; ++i) s += red[i];
      out[b] = s;
    }
  }
}

extern "C" void kernel_launch(void* const* d_in, const int* in_sizes, int n_in,
                              void* d_out, int out_size, void* d_ws, size_t ws_size,
                              hipStream_t stream) {
  (void)n_in; (void)out_size; (void)d_ws; (void)ws_size;
  const float* X   = (const float*)d_in[0];
  const float* Wh  = (const float*)d_in[1];
  const float* bh  = (const float*)d_in[2];
  const float* Wr  = (const float*)d_in[3];
  const float* Wq  = (const float*)d_in[4];
  const float* wtr = (const float*)d_in[5];
  const float* Wc  = (const float*)d_in[6];
  const float* bc  = (const float*)d_in[7];
  float* out = (float*)d_out;

  const int B = in_sizes[0] / (2 * HH * WW);   // 256
  vin_fused<<<B, 512, 0, stream>>>(X, Wh, bh, Wr, Wq, wtr, Wc, bc, out);
}

// Round 16
// 177.588 us; speedup vs baseline: 1.0426x; 1.0426x over previous
//
#include <hip/hip_runtime.h>

#define HH 64
#define WW 64
#define S  68          // padded LDS row stride (floats)
#define PH 66          // padded rows (1-px zero frame)
#define NLQ 10
#define NP  5          // channel pairs
#define NR 8           // rows per thread (512 threads = 8 waves = 2/SIMD)

typedef float f32x2 __attribute__((ext_vector_type(2)));

// One block per image (grid=256 = 1 block/CU). Thread t: column x=t&63, wave
// yg owns image rows y0..y0+7. v lives in registers (vv[10] = col x of rows
// y0-1..y0+8).
//
// Exchange-primitive bisect history:
//  R20 shfl_up/down + 1 barrier      -> FAIL (q 0.148)
//  R21 ds_bpermute  + 2 barriers     -> PASS (125us; bpermute = LDS pipe,
//                                       so the serialization remained)
//  R22 DPP wave_shl/shr + 1 barrier  -> FAIL (critic 0.09): DIRECTION SWAP.
//      ISA: WF_SL1 result[i]=src[i+1] (right neighbor, zeroes lane63);
//           WF_SR1 result[i]=src[i-1] (left  neighbor, zeroes lane0).
//  R23 (this) = R21 with ONLY the exchange swapped to corrected DPP:
//      vL = WF_SR1 (0x138), vR = WF_SL1 (0x130); BOTH barriers kept;
//      x==0/63 selects kept (immune to bound_ctrl semantics). DPP runs on
//      the VALU pipe -> 160 LDS ops/step removed vs R21.
__device__ __forceinline__ float dpp_wsr1(float v) {   // lane i <- lane i-1 (left nbr)
  return __int_as_float(__builtin_amdgcn_mov_dpp(__float_as_int(v), 0x138, 0xf, 0xf, true));
}
__device__ __forceinline__ float dpp_wsl1(float v) {   // lane i <- lane i+1 (right nbr)
  return __int_as_float(__builtin_amdgcn_mov_dpp(__float_as_int(v), 0x130, 0xf, 0xf, true));
}

__global__ __launch_bounds__(512)
__attribute__((amdgpu_waves_per_eu(2, 2)))
void vin_fused(
    const float* __restrict__ X,    // [B,2,64,64]
    const float* __restrict__ Wh,   // [150,2,3,3]
    const float* __restrict__ bh,   // [150]
    const float* __restrict__ Wr,   // [150]
    const float* __restrict__ Wq,   // [10,1,3,3]
    const float* __restrict__ wtr,  // [10,1,3,3] transition
    const float* __restrict__ Wc,   // [4096]
    const float* __restrict__ bc,   // [1]
    float* __restrict__ out)        // [256 critic] ++ [256*40960 q]
{
  __shared__ float vb[2][PH * S];     // X staging (r conv inputs)
  __shared__ float rb[PH * S];        // r (q0 conv input)
  __shared__ float hv[2][16][64];     // K-loop halo rows (parity, 2/wave)
  __shared__ float Wef[19];
  __shared__ float Wpart[152];
  __shared__ float red[8];

  const int b  = blockIdx.x;
  const int t  = threadIdx.x;
  const int x  = t & 63;
  const int yg = t >> 6;
  const int y0 = yg * NR;
  const int base0 = y0 * S + x;   // padded (y0, x) = window top-left

  // ---- zero LDS (frames must be 0; interiors overwritten) ----
  {
    float* vbf = &vb[0][0];
    for (int i = t; i < 2 * PH * S; i += 512) vbf[i] = 0.f;
    for (int i = t; i < PH * S; i += 512) rb[i] = 0.f;
  }
  __syncthreads();

  // ---- stage X into vb interiors; collapse 150-ch conv to Wef[19] ----
  const float* Xb = X + (size_t)b * (2 * HH * WW);
  for (int i = t; i < HH * WW; i += 512) {
    const int yy = i >> 6, xx = i & 63;
    vb[0][(yy + 1) * S + xx + 1] = Xb[i];
    vb[1][(yy + 1) * S + xx + 1] = Xb[HH * WW + i];
  }
  if (t < 152) {                       // parallel collapse: 19 outputs x 8 parts
    const int i = t >> 3, part = t & 7;
    float s = 0.f;
    if (i < 18) {
      for (int c = part; c < 150; c += 8) s += Wr[c] * Wh[c * 18 + i];
    } else {
      for (int c = part; c < 150; c += 8) s += Wr[c] * bh[c];
    }
    Wpart[t] = s;
  }
  __syncthreads();
  if (t < 19) {
    float s = 0.f;
#pragma unroll
    for (int k = 0; k < 8; ++k) s += Wpart[t * 8 + k];
    Wef[t] = s;
  }
  __syncthreads();

  // ---- r = conv(X, Weff, pad=1) + beff -> rb ----
  {
    float We[19];
#pragma unroll
    for (int i = 0; i < 19; ++i) We[i] = Wef[i];
#pragma unroll
    for (int j = 0; j < NR; ++j) {
      const int tb = base0 + j * S;
      float s = We[18];
#pragma unroll
      for (int dy = 0; dy < 3; ++dy)
#pragma unroll
        for (int dx = 0; dx < 3; ++dx) {
          const int idx = tb + dy * S + dx;
          s = fmaf(vb[0][idx], We[dy * 3 + dx], s);
          s = fmaf(vb[1][idx], We[9 + dy * 3 + dx], s);
        }
      rb[tb + S + 1] = s;
    }
  }
  __syncthreads();

  // ---- q0 = conv(r, Wq, pad=1) -> q0p pairs; v_init -> vv regs ----
  f32x2 q0p[NR][NP];
  float vv[10];                 // vv[0]=row y0-1 halo, vv[1..8]=own, vv[9]=halo
  {
    float win[NR + 2][3];
#pragma unroll
    for (int rr = 0; rr < NR + 2; ++rr) {
      const int a = base0 + rr * S;
      win[rr][0] = rb[a];
      win[rr][1] = rb[a + 1];
      win[rr][2] = rb[a + 2];
    }
    f32x2 mm[NR];
#pragma unroll
    for (int p = 0; p < NP; ++p) {
      f32x2 w[9];
#pragma unroll
      for (int k = 0; k < 9; ++k)
        w[k] = (f32x2){ Wq[(2 * p) * 9 + k], Wq[(2 * p + 1) * 9 + k] };
#pragma unroll
      for (int j = 0; j < NR; ++j) {
        f32x2 acc = (f32x2){0.f, 0.f};
#pragma unroll
        for (int dy = 0; dy < 3; ++dy)
#pragma unroll
          for (int dx = 0; dx < 3; ++dx) {
            const float wv = win[j + dy][dx];
            acc = __builtin_elementwise_fma(w[dy * 3 + dx], (f32x2){wv, wv}, acc);
          }
        q0p[j][p] = acc;
        mm[j] = (p == 0) ? acc : __builtin_elementwise_max(mm[j], acc);
      }
    }
#pragma unroll
    for (int j = 0; j < NR; ++j) vv[j + 1] = fmaxf(mm[j].x, mm[j].y);
  }

  // ---- transition weight pairs (persistent) ----
  f32x2 wtp[NP][9];
#pragma unroll
  for (int p = 0; p < NP; ++p)
#pragma unroll
    for (int k = 0; k < 9; ++k)
      wtp[p][k] = (f32x2){ wtr[(2 * p) * 9 + k], wtr[(2 * p + 1) * 9 + k] };

  __syncthreads();   // staging done; hv safe to use

  // ---- K-loop: 39 v-updates, all state in registers ----
#pragma unroll 1
  for (int it = 0; it < 39; ++it) {
    const int pb = it & 1;
    // vertical halo exchange: write own top/bottom, barrier, read, barrier
    hv[pb][yg * 2][x]     = vv[1];
    hv[pb][yg * 2 + 1][x] = vv[8];
    __syncthreads();
    vv[0] = (yg > 0) ? hv[pb][yg * 2 - 1][x] : 0.f;
    vv[9] = (yg < 7) ? hv[pb][yg * 2 + 2][x] : 0.f;
    __syncthreads();   // reads complete before anyone's next-iteration writes

    // horizontal neighbors on the VALU pipe (corrected DPP); frame via select
    float vL[10], vR[10];
#pragma unroll
    for (int r = 0; r < 10; ++r) {
      const float l = dpp_wsr1(vv[r]);   // lane i <- lane i-1
      const float rr_ = dpp_wsl1(vv[r]); // lane i <- lane i+1
      vL[r] = (x == 0)  ? 0.f : l;
      vR[r] = (x == 63) ? 0.f : rr_;
    }

    f32x2 mm[NR];
#pragma unroll
    for (int p = 0; p < NP; ++p) {
      f32x2 w[9];
#pragma unroll
      for (int k = 0; k < 9; ++k) w[k] = wtp[p][k];
#pragma unroll
      for (int j = 0; j < NR; ++j) {
        f32x2 acc = q0p[j][p];
        acc = __builtin_elementwise_fma(w[0], (f32x2){vL[j],     vL[j]},     acc);
        acc = __builtin_elementwise_fma(w[1], (f32x2){vv[j],     vv[j]},     acc);
        acc = __builtin_elementwise_fma(w[2], (f32x2){vR[j],     vR[j]},     acc);
        acc = __builtin_elementwise_fma(w[3], (f32x2){vL[j + 1], vL[j + 1]}, acc);
        acc = __builtin_elementwise_fma(w[4], (f32x2){vv[j + 1], vv[j + 1]}, acc);
        acc = __builtin_elementwise_fma(w[5], (f32x2){vR[j + 1], vR[j + 1]}, acc);
        acc = __builtin_elementwise_fma(w[6], (f32x2){vL[j + 2], vL[j + 2]}, acc);
        acc = __builtin_elementwise_fma(w[7], (f32x2){vv[j + 2], vv[j + 2]}, acc);
        acc = __builtin_elementwise_fma(w[8], (f32x2){vR[j + 2], vR[j + 2]}, acc);
        mm[j] = (p == 0) ? acc : __builtin_elementwise_max(mm[j], acc);
      }
    }
#pragma unroll
    for (int j = 0; j < NR; ++j) vv[j + 1] = fmaxf(mm[j].x, mm[j].y);
  }

  // ---- final iteration (it=39): emit q + critic dot ----
  {
    const int pb = 39 & 1;
    hv[pb][yg * 2][x]     = vv[1];
    hv[pb][yg * 2 + 1][x] = vv[8];
    __syncthreads();
    vv[0] = (yg > 0) ? hv[pb][yg * 2 - 1][x] : 0.f;
    vv[9] = (yg < 7) ? hv[pb][yg * 2 + 2][x] : 0.f;
    __syncthreads();

    float vL[10], vR[10];
#pragma unroll
    for (int r = 0; r < 10; ++r) {
      const float l = dpp_wsr1(vv[r]);
      const float rr_ = dpp_wsl1(vv[r]);
      vL[r] = (x == 0)  ? 0.f : l;
      vR[r] = (x == 63) ? 0.f : rr_;
    }

    float wcv[NR];
#pragma unroll
    for (int j = 0; j < NR; ++j) wcv[j] = Wc[(y0 + j) * WW + x];

    float* qo = out + 256 + (size_t)b * (NLQ * HH * WW) + y0 * WW + x;
    f32x2 mm[NR];
#pragma unroll
    for (int p = 0; p < NP; ++p) {
      f32x2 w[9];
#pragma unroll
      for (int k = 0; k < 9; ++k) w[k] = wtp[p][k];
#pragma unroll
      for (int j = 0; j < NR; ++j) {
        f32x2 acc = q0p[j][p];
        acc = __builtin_elementwise_fma(w[0], (f32x2){vL[j],     vL[j]},     acc);
        acc = __builtin_elementwise_fma(w[1], (f32x2){vv[j],     vv[j]},     acc);
        acc = __builtin_elementwise_fma(w[2], (f32x2){vR[j],     vR[j]},     acc);
        acc = __builtin_elementwise_fma(w[3], (f32x2){vL[j + 1], vL[j + 1]}, acc);
        acc = __builtin_elementwise_fma(w[4], (f32x2){vv[j + 1], vv[j + 1]}, acc);
        acc = __builtin_elementwise_fma(w[5], (f32x2){vR[j + 1], vR[j + 1]}, acc);
        acc = __builtin_elementwise_fma(w[6], (f32x2){vL[j + 2], vL[j + 2]}, acc);
        acc = __builtin_elementwise_fma(w[7], (f32x2){vv[j + 2], vv[j + 2]}, acc);
        acc = __builtin_elementwise_fma(w[8], (f32x2){vR[j + 2], vR[j + 2]}, acc);
        qo[(2 * p)     * (HH * WW) + j * WW] = acc.x;
        qo[(2 * p + 1) * (HH * WW) + j * WW] = acc.y;
        mm[j] = (p == 0) ? acc : __builtin_elementwise_max(mm[j], acc);
      }
    }
    float acc_c = 0.f;
#pragma unroll
    for (int j = 0; j < NR; ++j)
      acc_c = fmaf(fmaxf(mm[j].x, mm[j].y), wcv[j], acc_c);

    // ---- block-reduce critic ----
#pragma unroll
    for (int off = 32; off > 0; off >>= 1) acc_c += __shfl_down(acc_c, off);
    if (x == 0) red[yg] = acc_c;
    __syncthreads();
    if (t == 0) {
      float s = bc[0];
#pragma unroll
      for (int i = 0; i < 8; ++i) s += red[i];
      out[b] = s;
    }
  }
}

extern "C" void kernel_launch(void* const* d_in, const int* in_sizes, int n_in,
                              void* d_out, int out_size, void* d_ws, size_t ws_size,
                              hipStream_t stream) {
  (void)n_in; (void)out_size; (void)d_ws; (void)ws_size;
  const float* X   = (const float*)d_in[0];
  const float* Wh  = (const float*)d_in[1];
  const float* bh  = (const float*)d_in[2];
  const float* Wr  = (const float*)d_in[3];
  const float* Wq  = (const float*)d_in[4];
  const float* wtr = (const float*)d_in[5];
  const float* Wc  = (const float*)d_in[6];
  const float* bc  = (const float*)d_in[7];
  float* out = (float*)d_out;

  const int B = in_sizes[0] / (2 * HH * WW);   // 256
  vin_fused<<<B, 512, 0, stream>>>(X, Wh, bh, Wr, Wq, wtr, Wc, bc, out);
}